// Round 5
// baseline (548.191 us; speedup 1.0000x reference)
//
#include <hip/hip_runtime.h>

typedef __bf16 bf16x8 __attribute__((ext_vector_type(8)));
typedef float f32x4 __attribute__((ext_vector_type(4)));
typedef unsigned int u32;

#define SEQ_    2048
#define DM_     1024
#define DI_     2048
#define BATCH_  2
#define MTOT    4096   // BATCH_*SEQ_
#define DSTATE  16
#define DTRANK  64
#define XDBLN   96
#define LCH     64
#define NCH     32     // SEQ_/LCH

__device__ __forceinline__ float bf2f(unsigned short u){ return __uint_as_float(((unsigned)u) << 16); }
__device__ __forceinline__ unsigned short f2bf(float f){
  unsigned u = __float_as_uint(f);
  return (unsigned short)((u + 0x7fffu + ((u >> 16) & 1u)) >> 16);  // RNE
}
__device__ __forceinline__ float silu_f(float v){ return v / (1.f + __expf(-v)); }
__device__ __forceinline__ float softplus_f(float v){ return v > 20.f ? v : log1pf(__expf(v)); }

__device__ __forceinline__ void load_lds16(const void* g, void* l){
  __builtin_amdgcn_global_load_lds((const __attribute__((address_space(1))) u32*)g,
                                   (__attribute__((address_space(3))) u32*)l, 16, 0, 0);
}

// ---------------- fp32 -> bf16 convert (vectorized) ----------------
__global__ __launch_bounds__(256) void k_f2bf(const float* __restrict__ in, unsigned short* __restrict__ out, int n){
  int i = (blockIdx.x*256 + threadIdx.x)*4;
  if (i < n){
    float4 v = *(const float4*)(in + i);
    ushort4 o; o.x = f2bf(v.x); o.y = f2bf(v.y); o.z = f2bf(v.z); o.w = f2bf(v.w);
    *(ushort4*)(out + i) = o;
  }
}

// W_x (96,2048) fp32 -> padded (128,2048) bf16, rows 96..127 zero
__global__ __launch_bounds__(256) void k_wxpad(const float* __restrict__ wx, unsigned short* __restrict__ out){
  int i = (blockIdx.x*256 + threadIdx.x)*4;   // over 128*2048
  int row = i >> 11;
  ushort4 o;
  if (row < 96){
    float4 v = *(const float4*)(wx + i);
    o.x = f2bf(v.x); o.y = f2bf(v.y); o.z = f2bf(v.z); o.w = f2bf(v.w);
  } else { o.x = 0; o.y = 0; o.z = 0; o.w = 0; }
  *(ushort4*)(out + i) = o;
}

// extract x_dbl[:, 0:64] -> bf16 [MTOT][64]
__global__ __launch_bounds__(256) void k_xdt(const float* __restrict__ xdbl, unsigned short* __restrict__ out){
  int i = (blockIdx.x*256 + threadIdx.x)*4;   // over MTOT*64
  int m = i >> 6, k = i & 63;
  float4 v = *(const float4*)(xdbl + (size_t)m*XDBLN + k);
  ushort4 o; o.x = f2bf(v.x); o.y = f2bf(v.y); o.z = f2bf(v.z); o.w = f2bf(v.w);
  *(ushort4*)(out + i) = o;
}

// ---------------- bf16 MFMA GEMM: C[M,N] = A[M,K] * B[N,K]^T ----------------
template<int MODE>
__global__ __launch_bounds__(256) void k_gemm(const unsigned short* __restrict__ A,
                                              const unsigned short* __restrict__ Bw,
                                              int K,
                                              float* __restrict__ oF,
                                              unsigned short* __restrict__ oB0,
                                              unsigned short* __restrict__ oB1,
                                              const float* __restrict__ bias,
                                              int ldo, int nvalid)
{
  __shared__ unsigned short lA[2][128*32];
  __shared__ unsigned short lB[2][128*32];
  const int tid  = threadIdx.x;
  const unsigned short* Ab = A  + (size_t)blockIdx.y * 128 * K;
  const unsigned short* Bb = Bw + (size_t)blockIdx.x * 128 * K;

  const int lane = tid & 63;
  const int wv = tid >> 6;
  const int wm = wv >> 1, wn = wv & 1;   // 2x2 wave grid, each wave 64x64
  const int lr = lane & 15, lg = lane >> 4;

  f32x4 acc[4][4] = {};
  const int nk = K >> 5;
  int cur = 0;

  // prologue stage kt=0 into buf 0
  #pragma unroll
  for (int c = 0; c < 2; ++c){
    int e = (c*256 + tid)*8;            // element index within 128x32 tile
    int r = e >> 5, cl = e & 31;
    load_lds16(Ab + (size_t)r*K + cl, &lA[0][e]);
    load_lds16(Bb + (size_t)r*K + cl, &lB[0][e]);
  }

  for (int kt = 0; kt < nk; ++kt){
    __syncthreads();                    // staged buf[cur] visible; prev buf free
    if (kt + 1 < nk){
      int k0 = (kt + 1) * 32;
      int nb = cur ^ 1;
      #pragma unroll
      for (int c = 0; c < 2; ++c){
        int e = (c*256 + tid)*8;
        int r = e >> 5, cl = e & 31;
        load_lds16(Ab + (size_t)r*K + k0 + cl, &lA[nb][e]);
        load_lds16(Bb + (size_t)r*K + k0 + cl, &lB[nb][e]);
      }
    }
    bf16x8 af[4], bfr[4];
    #pragma unroll
    for (int mi = 0; mi < 4; ++mi)
      af[mi] = *(const bf16x8*)&lA[cur][(wm*64 + mi*16 + lr)*32 + lg*8];
    #pragma unroll
    for (int ni = 0; ni < 4; ++ni)
      bfr[ni] = *(const bf16x8*)&lB[cur][(wn*64 + ni*16 + lr)*32 + lg*8];
    #pragma unroll
    for (int mi = 0; mi < 4; ++mi)
      #pragma unroll
      for (int ni = 0; ni < 4; ++ni)
        acc[mi][ni] = __builtin_amdgcn_mfma_f32_16x16x32_bf16(af[mi], bfr[ni], acc[mi][ni], 0, 0, 0);
    cur ^= 1;
  }

  // epilogue: D row = (lane>>4)*4 + reg, col = lane&15  [m89-verified]
  const int rowB = blockIdx.y*128 + wm*64;
  const int colB = blockIdx.x*128 + wn*64;
  #pragma unroll
  for (int mi = 0; mi < 4; ++mi){
    #pragma unroll
    for (int ni = 0; ni < 4; ++ni){
      int col = colB + ni*16 + lr;
      #pragma unroll
      for (int r = 0; r < 4; ++r){
        int row = rowB + mi*16 + lg*4 + r;
        float v = acc[mi][ni][r];
        if (MODE == 0){
          if (col < DI_) oB0[(size_t)row*DI_ + col] = f2bf(v);
          else           oB1[(size_t)row*DI_ + (col - DI_)] = f2bf(silu_f(v));
        } else if (MODE == 1){
          if (col < nvalid) oF[(size_t)row*ldo + col] = v;
        } else if (MODE == 2){
          oF[(size_t)row*ldo + col] = softplus_f(v + bias[col]);
        } else {
          oF[(size_t)row*ldo + col] = v;
        }
      }
    }
  }
}

// ---------------- ABLATION clones of k_gemm<0> (write to dead scratch) ----------
// ABL=1: no epilogue (acc kept live via asm)     -> isolates store cost
// ABL=3: no ds_read (af/bfr=0; stage+bar+MFMA)   -> isolates LDS-read cost
// ABL=4: no staging (ds_read junk; bar kept)     -> isolates stage/vmcnt-drain cost
// ABL=5: full + both-sides XOR swizzle (T2)      -> direct swizzle A/B on this shape
template<int ABL>
__device__ __forceinline__ void abl_body(const unsigned short* __restrict__ A,
                                         const unsigned short* __restrict__ Bw,
                                         unsigned short* __restrict__ scr)
{
  __shared__ unsigned short lA[2][128*32];
  __shared__ unsigned short lB[2][128*32];
  const int K = 1024;
  const int tid  = threadIdx.x;
  const unsigned short* Ab = A  + (size_t)blockIdx.y * 128 * K;
  const unsigned short* Bb = Bw + (size_t)blockIdx.x * 128 * K;
  const int lane = tid & 63;
  const int wv = tid >> 6;
  const int wm = wv >> 1, wn = wv & 1;
  const int lr = lane & 15, lg = lane >> 4;

  f32x4 acc[4][4] = {};
  const int nk = K >> 5;
  int cur = 0;

  if (ABL != 4){
    #pragma unroll
    for (int c = 0; c < 2; ++c){
      int e = (c*256 + tid)*8;
      int r = e >> 5, s = (e >> 3) & 3;
      int cl = (ABL == 5) ? ((s ^ ((r >> 1) & 3)) << 3) : (e & 31);
      load_lds16(Ab + (size_t)r*K + cl, &lA[0][e]);
      load_lds16(Bb + (size_t)r*K + cl, &lB[0][e]);
    }
  }

  for (int kt = 0; kt < nk; ++kt){
    __syncthreads();
    if (ABL != 4 && kt + 1 < nk){
      int k0 = (kt + 1) * 32;
      int nb = cur ^ 1;
      #pragma unroll
      for (int c = 0; c < 2; ++c){
        int e = (c*256 + tid)*8;
        int r = e >> 5, s = (e >> 3) & 3;
        int cl = (ABL == 5) ? ((s ^ ((r >> 1) & 3)) << 3) : (e & 31);
        load_lds16(Ab + (size_t)r*K + k0 + cl, &lA[nb][e]);
        load_lds16(Bb + (size_t)r*K + k0 + cl, &lB[nb][e]);
      }
    }
    bf16x8 af[4] = {}, bfr[4] = {};
    if (ABL != 3){
      #pragma unroll
      for (int mi = 0; mi < 4; ++mi){
        int row = wm*64 + mi*16 + lr;
        int slot = (ABL == 5) ? (lg ^ ((row >> 1) & 3)) : lg;
        af[mi] = *(const bf16x8*)&lA[cur][row*32 + slot*8];
      }
      #pragma unroll
      for (int ni = 0; ni < 4; ++ni){
        int row = wn*64 + ni*16 + lr;
        int slot = (ABL == 5) ? (lg ^ ((row >> 1) & 3)) : lg;
        bfr[ni] = *(const bf16x8*)&lB[cur][row*32 + slot*8];
      }
    }
    #pragma unroll
    for (int mi = 0; mi < 4; ++mi)
      #pragma unroll
      for (int ni = 0; ni < 4; ++ni)
        acc[mi][ni] = __builtin_amdgcn_mfma_f32_16x16x32_bf16(af[mi], bfr[ni], acc[mi][ni], 0, 0, 0);
    cur ^= 1;
  }

  const int rowB = blockIdx.y*128 + wm*64;
  const int colB = blockIdx.x*128 + wn*64;
  if (ABL == 1){
    #pragma unroll
    for (int mi = 0; mi < 4; ++mi)
      #pragma unroll
      for (int ni = 0; ni < 4; ++ni)
        #pragma unroll
        for (int r = 0; r < 4; ++r)
          asm volatile("" :: "v"(acc[mi][ni][r]));   // keep MFMAs live, no stores (rule 17)
  } else {
    #pragma unroll
    for (int mi = 0; mi < 4; ++mi)
      #pragma unroll
      for (int ni = 0; ni < 4; ++ni){
        int col = colB + ni*16 + lr;
        #pragma unroll
        for (int r = 0; r < 4; ++r){
          int row = rowB + mi*16 + lg*4 + r;
          scr[(size_t)row*4096 + col] = f2bf(acc[mi][ni][r]);
        }
      }
  }
}
__global__ __launch_bounds__(256) void k_abl1(const unsigned short* __restrict__ A, const unsigned short* __restrict__ B, unsigned short* __restrict__ s){ abl_body<1>(A,B,s); }
__global__ __launch_bounds__(256) void k_abl3(const unsigned short* __restrict__ A, const unsigned short* __restrict__ B, unsigned short* __restrict__ s){ abl_body<3>(A,B,s); }
__global__ __launch_bounds__(256) void k_abl4(const unsigned short* __restrict__ A, const unsigned short* __restrict__ B, unsigned short* __restrict__ s){ abl_body<4>(A,B,s); }
__global__ __launch_bounds__(256) void k_abl5(const unsigned short* __restrict__ A, const unsigned short* __restrict__ B, unsigned short* __restrict__ s){ abl_body<5>(A,B,s); }

// ---------------- depthwise causal conv(4) + SiLU ----------------
__global__ __launch_bounds__(256) void k_conv(const unsigned short* __restrict__ xb, const float* __restrict__ w,
                                              const float* __restrict__ cb, unsigned short* __restrict__ ub)
{
  const int d  = blockIdx.x*256 + threadIdx.x;
  const int t0 = blockIdx.y*64;
  const int b  = blockIdx.z;
  const float w0 = w[d*4+0], w1 = w[d*4+1], w2 = w[d*4+2], w3 = w[d*4+3], bias = cb[d];
  const size_t base = (size_t)(b*SEQ_)*DI_ + d;
  float xm3 = 0.f, xm2 = 0.f, xm1 = 0.f;
  if (t0 > 0){
    xm3 = bf2f(xb[base + (size_t)(t0-3)*DI_]);
    xm2 = bf2f(xb[base + (size_t)(t0-2)*DI_]);
    xm1 = bf2f(xb[base + (size_t)(t0-1)*DI_]);
  }
  for (int t = t0; t < t0 + 64; ++t){
    float xc = bf2f(xb[base + (size_t)t*DI_]);
    float acc = w0*xm3 + w1*xm2 + w2*xm1 + w3*xc + bias;
    ub[base + (size_t)t*DI_] = f2bf(silu_f(acc));
    xm3 = xm2; xm2 = xm1; xm1 = xc;
  }
}

// ---------------- chunked selective scan ----------------
__global__ __launch_bounds__(256) void k_scanA(const float* __restrict__ dtf, const unsigned short* __restrict__ ub,
                                               const float* __restrict__ xdbl, const float* __restrict__ alog,
                                               float* __restrict__ hloc, float* __restrict__ pprod)
{
  const int d = blockIdx.x*256 + threadIdx.x;
  const int c = blockIdx.y, b = blockIdx.z;
  __shared__ float sB[LCH][DSTATE];
  const size_t rowbase = (size_t)(b*SEQ_ + c*LCH);
  for (int i = threadIdx.x; i < LCH*DSTATE; i += 256){
    int t = i >> 4, n = i & 15;
    sB[t][n] = xdbl[(rowbase + t)*XDBLN + DTRANK + n];
  }
  __syncthreads();
  float a[16], h[16], p[16];
  #pragma unroll
  for (int n = 0; n < 16; ++n){
    a[n] = -__expf(alog[(size_t)d*16 + n]);
    h[n] = 0.f; p[n] = 1.f;
  }
  const size_t base = rowbase*DI_ + d;
  for (int t = 0; t < LCH; ++t){
    float dtv = dtf[base + (size_t)t*DI_];
    float uv  = bf2f(ub[base + (size_t)t*DI_]);
    float du  = dtv*uv;
    #pragma unroll
    for (int n = 0; n < 16; ++n){
      float da = __expf(dtv*a[n]);
      h[n] = da*h[n] + du*sB[t][n];
      p[n] *= da;
    }
  }
  const size_t o = ((size_t)(b*NCH + c)*DI_ + d)*16;
  #pragma unroll
  for (int n = 0; n < 16; ++n){ hloc[o+n] = h[n]; pprod[o+n] = p[n]; }
}

__global__ __launch_bounds__(256) void k_scanB(const float* __restrict__ hloc, const float* __restrict__ pprod,
                                               float* __restrict__ hinit)
{
  int i = blockIdx.x*256 + threadIdx.x;  // over BATCH_*DI_*16
  int b = i >> 15;
  int r = i & 32767;
  int d = r >> 4, n = r & 15;
  float H = 0.f;
  for (int c = 0; c < NCH; ++c){
    size_t o = ((size_t)(b*NCH + c)*DI_ + d)*16 + n;
    hinit[o] = H;
    H = pprod[o]*H + hloc[o];
  }
}

__global__ __launch_bounds__(256) void k_scanC(const float* __restrict__ dtf, const unsigned short* __restrict__ ub,
                                               const float* __restrict__ xdbl, const float* __restrict__ alog,
                                               const float* __restrict__ hinit, const float* __restrict__ Dvec,
                                               const unsigned short* __restrict__ sresb, unsigned short* __restrict__ yg)
{
  const int d = blockIdx.x*256 + threadIdx.x;
  const int c = blockIdx.y, b = blockIdx.z;
  __shared__ float sBC[LCH][32];   // [t][0..15]=B, [16..31]=C
  const size_t rowbase = (size_t)(b*SEQ_ + c*LCH);
  for (int i = threadIdx.x; i < LCH*32; i += 256){
    int t = i >> 5, j = i & 31;
    sBC[t][j] = xdbl[(rowbase + t)*XDBLN + DTRANK + j];
  }
  __syncthreads();
  float a[16], h[16];
  const size_t o = ((size_t)(b*NCH + c)*DI_ + d)*16;
  #pragma unroll
  for (int n = 0; n < 16; ++n){
    a[n] = -__expf(alog[(size_t)d*16 + n]);
    h[n] = hinit[o + n];
  }
  const float Dd = Dvec[d];
  const size_t base = rowbase*DI_ + d;
  for (int t = 0; t < LCH; ++t){
    float dtv = dtf[base + (size_t)t*DI_];
    float uv  = bf2f(ub[base + (size_t)t*DI_]);
    float du  = dtv*uv;
    float y = 0.f;
    #pragma unroll
    for (int n = 0; n < 16; ++n){
      float da = __expf(dtv*a[n]);
      h[n] = da*h[n] + du*sBC[t][n];
      y += h[n]*sBC[t][16+n];
    }
    y += Dd*uv;
    float g = bf2f(sresb[base + (size_t)t*DI_]);
    yg[base + (size_t)t*DI_] = f2bf(y*g);
  }
}

extern "C" void kernel_launch(void* const* d_in, const int* in_sizes, int n_in,
                              void* d_out, int out_size, void* d_ws, size_t ws_size,
                              hipStream_t stream)
{
  const float* hs    = (const float*)d_in[0];
  const float* Win   = (const float*)d_in[1];
  const float* convw = (const float*)d_in[2];
  const float* convb = (const float*)d_in[3];
  const float* Wx    = (const float*)d_in[4];
  const float* Wdt   = (const float*)d_in[5];
  const float* bdt   = (const float*)d_in[6];
  const float* Alog  = (const float*)d_in[7];
  const float* Dvec  = (const float*)d_in[8];
  const float* Wout  = (const float*)d_in[9];
  float* out = (float*)d_out;

  char* p = (char*)d_ws;
  auto take = [&](size_t bytes) -> char* {
    char* r = p; p += (bytes + 255) & ~(size_t)255; return r;
  };
  unsigned short* hsb   = (unsigned short*)take((size_t)MTOT*DM_*2);
  unsigned short* winb  = (unsigned short*)take((size_t)2*DI_*DM_*2);
  unsigned short* woutb = (unsigned short*)take((size_t)DM_*DI_*2);
  unsigned short* wxpb  = (unsigned short*)take((size_t)128*DI_*2);
  unsigned short* wdtb  = (unsigned short*)take((size_t)DI_*DTRANK*2);
  unsigned short* xb    = (unsigned short*)take((size_t)MTOT*DI_*2);
  unsigned short* sresb = (unsigned short*)take((size_t)MTOT*DI_*2);  // contiguous after xb (both 256-mult)
  unsigned short* ub    = (unsigned short*)take((size_t)MTOT*DI_*2);
  float*          xdbl  = (float*)take((size_t)MTOT*XDBLN*4);
  unsigned short* xdtb  = (unsigned short*)take((size_t)MTOT*DTRANK*2);
  float*          dtf   = (float*)take((size_t)MTOT*DI_*4);
  float*          hloc  = (float*)take((size_t)BATCH_*NCH*DI_*16*4);
  float*          pprod = (float*)take((size_t)BATCH_*NCH*DI_*16*4);
  float*          hinit = (float*)take((size_t)BATCH_*NCH*DI_*16*4);
  unsigned short* yg    = (unsigned short*)take((size_t)MTOT*DI_*2);
  if ((size_t)(p - (char*)d_ws) > ws_size) return;

  // dtype converts
  k_f2bf <<<(MTOT*DM_/4 + 255)/256, 256, 0, stream>>>(hs,  hsb,  MTOT*DM_);
  k_f2bf <<<(2*DI_*DM_/4 + 255)/256, 256, 0, stream>>>(Win, winb, 2*DI_*DM_);
  k_f2bf <<<(DM_*DI_/4 + 255)/256, 256, 0, stream>>>(Wout, woutb, DM_*DI_);
  k_f2bf <<<(DI_*DTRANK/4 + 255)/256, 256, 0, stream>>>(Wdt, wdtb, DI_*DTRANK);
  k_wxpad<<<(128*DI_/4)/256, 256, 0, stream>>>(Wx, wxpb);

  // in-projection: xr = hs @ W_in^T ; split -> x (bf16), silu(res) (bf16)
  k_gemm<0><<<dim3(32, 32), 256, 0, stream>>>(hsb, winb, DM_, nullptr, xb, sresb, nullptr, 0, 0);

  // depthwise conv + silu -> u (bf16)
  k_conv<<<dim3(DI_/256, SEQ_/64, BATCH_), 256, 0, stream>>>(xb, convw, convb, ub);

  // x_dbl = u @ W_x^T (N padded 96->128)
  k_gemm<1><<<dim3(1, 32), 256, 0, stream>>>(ub, wxpb, DI_, xdbl, nullptr, nullptr, nullptr, XDBLN, XDBLN);
  k_xdt<<<(MTOT*DTRANK/4)/256, 256, 0, stream>>>(xdbl, xdtb);

  // dt = softplus(x_dbl[:, :64] @ W_dt^T + b_dt)
  k_gemm<2><<<dim3(16, 32), 256, 0, stream>>>(xdtb, wdtb, DTRANK, dtf, nullptr, nullptr, bdt, DI_, DI_);

  // chunked selective scan
  k_scanA<<<dim3(DI_/256, NCH, BATCH_), 256, 0, stream>>>(dtf, ub, xdbl, Alog, hloc, pprod);
  k_scanB<<<(BATCH_*DI_*16)/256, 256, 0, stream>>>(hloc, pprod, hinit);
  k_scanC<<<dim3(DI_/256, NCH, BATCH_), 256, 0, stream>>>(dtf, ub, xdbl, Alog, hinit, Dvec, sresb, yg);

  // final projection: out = (y * silu(res)) @ W_out^T
  k_gemm<3><<<dim3(DM_/128, 32), 256, 0, stream>>>(yg, woutb, DI_, out, nullptr, nullptr, nullptr, DM_, DM_);

  // ---- diagnostic ablations of k_gemm<0> (scratch = xb∪sresb, dead here;
  //      fully rewritten by k_gemm<0> next replay -> deterministic) ----
  k_abl1<<<dim3(32, 32), 256, 0, stream>>>(hsb, winb, xb);
  k_abl3<<<dim3(32, 32), 256, 0, stream>>>(hsb, winb, xb);
  k_abl4<<<dim3(32, 32), 256, 0, stream>>>(hsb, winb, xb);
  k_abl5<<<dim3(32, 32), 256, 0, stream>>>(hsb, winb, xb);
}

// Round 6
// 315.740 us; speedup vs baseline: 1.7362x; 1.7362x over previous
//
#include <hip/hip_runtime.h>

typedef __bf16 bf16x8 __attribute__((ext_vector_type(8)));
typedef float f32x4 __attribute__((ext_vector_type(4)));
typedef unsigned short u16x8 __attribute__((ext_vector_type(8)));
typedef unsigned int u32;

#define SEQ_    2048
#define DM_     1024
#define DI_     2048
#define BATCH_  2
#define MTOT    4096   // BATCH_*SEQ_
#define DSTATE  16
#define DTRANK  64
#define XDBLN   96
#define LCH     64
#define NCH     32     // SEQ_/LCH

__device__ __forceinline__ float bf2f(unsigned short u){ return __uint_as_float(((unsigned)u) << 16); }
__device__ __forceinline__ unsigned short f2bf(float f){
  unsigned u = __float_as_uint(f);
  return (unsigned short)((u + 0x7fffu + ((u >> 16) & 1u)) >> 16);  // RNE
}
__device__ __forceinline__ float silu_f(float v){ return v / (1.f + __expf(-v)); }
__device__ __forceinline__ float softplus_f(float v){ return v > 20.f ? v : log1pf(__expf(v)); }

__device__ __forceinline__ void load_lds16(const void* g, void* l){
  __builtin_amdgcn_global_load_lds((const __attribute__((address_space(1))) u32*)g,
                                   (__attribute__((address_space(3))) u32*)l, 16, 0, 0);
}

// ---------------- fp32 -> bf16 convert (vectorized) ----------------
__global__ __launch_bounds__(256) void k_f2bf(const float* __restrict__ in, unsigned short* __restrict__ out, int n){
  int i = (blockIdx.x*256 + threadIdx.x)*4;
  if (i < n){
    float4 v = *(const float4*)(in + i);
    ushort4 o; o.x = f2bf(v.x); o.y = f2bf(v.y); o.z = f2bf(v.z); o.w = f2bf(v.w);
    *(ushort4*)(out + i) = o;
  }
}

// W_x (96,2048) fp32 -> padded (128,2048) bf16, rows 96..127 zero
__global__ __launch_bounds__(256) void k_wxpad(const float* __restrict__ wx, unsigned short* __restrict__ out){
  int i = (blockIdx.x*256 + threadIdx.x)*4;   // over 128*2048
  int row = i >> 11;
  ushort4 o;
  if (row < 96){
    float4 v = *(const float4*)(wx + i);
    o.x = f2bf(v.x); o.y = f2bf(v.y); o.z = f2bf(v.z); o.w = f2bf(v.w);
  } else { o.x = 0; o.y = 0; o.z = 0; o.w = 0; }
  *(ushort4*)(out + i) = o;
}

// extract x_dbl[:, 0:64] -> bf16 [MTOT][64]
__global__ __launch_bounds__(256) void k_xdt(const float* __restrict__ xdbl, unsigned short* __restrict__ out){
  int i = (blockIdx.x*256 + threadIdx.x)*4;   // over MTOT*64
  int m = i >> 6, k = i & 63;
  float4 v = *(const float4*)(xdbl + (size_t)m*XDBLN + k);
  ushort4 o; o.x = f2bf(v.x); o.y = f2bf(v.y); o.z = f2bf(v.z); o.w = f2bf(v.w);
  *(ushort4*)(out + i) = o;
}

// ---------------- bf16 MFMA GEMM: C[M,N] = A[M,K] * B[N,K]^T ----------------
// m97 structure + round-5 fixes:
//  - Both-sides XOR swizzle (T2-style): stage LDS[r][s] <- G[r][s ^ p(r)], p(r)=(r>>1)&3,
//    read slot = lg ^ p(row). Involution => exact. A and B share per-lane k-perm =>
//    MFMA dot products invariant. Read conflicts 8-way -> 2-way (free, m136).
//  - LDS-packed epilogue (all modes): reuse dead staging LDS per-wave
//    (bf16 stride-72 / fp32 stride-36; write-conflict-free, 16B-aligned rows),
//    emit 16B coalesced stores instead of scattered 2B/4B.
// MODE 0: split cols [0,2048)->x bf16, [2048,4096)->silu->sres bf16
// MODE 1: fp32 store cols < nvalid (x_dbl)
// MODE 2: softplus(acc + bias[col]) -> fp32 (dt)
// MODE 3: plain fp32 store (final output)
template<int MODE>
__global__ __launch_bounds__(256) void k_gemm(const unsigned short* __restrict__ A,
                                              const unsigned short* __restrict__ Bw,
                                              int K,
                                              float* __restrict__ oF,
                                              unsigned short* __restrict__ oB0,
                                              unsigned short* __restrict__ oB1,
                                              const float* __restrict__ bias,
                                              int ldo, int nvalid)
{
  __shared__ unsigned short smraw[18432];   // 36864 B: [0,16384) staging; whole = epilogue pack
  unsigned short* lA0 = smraw;              // [2][128*32] A buffers
  unsigned short* lB0 = smraw + 8192;       // [2][128*32] B buffers
  const int tid  = threadIdx.x;
  const unsigned short* Ab = A  + (size_t)blockIdx.y * 128 * K;
  const unsigned short* Bb = Bw + (size_t)blockIdx.x * 128 * K;

  const int lane = tid & 63;
  const int wv = tid >> 6;
  const int wm = wv >> 1, wn = wv & 1;   // 2x2 wave grid, each wave 64x64
  const int lr = lane & 15, lg = lane >> 4;

  f32x4 acc[4][4] = {};
  const int nk = K >> 5;
  int cur = 0;

  // staging geometry: lane covers 16B at linear LDS offset e; source col swizzled by p(r)
  const int e0 = tid*8;                    // c=0 element
  const int sl = tid & 3;                  // k-slot within row
  // prologue stage kt=0 into buf 0
  #pragma unroll
  for (int c = 0; c < 2; ++c){
    int e = c*2048 + e0;
    int r = e >> 5;
    int cl = (sl ^ ((r >> 1) & 3)) << 3;
    load_lds16(Ab + (size_t)r*K + cl, lA0 + e);
    load_lds16(Bb + (size_t)r*K + cl, lB0 + e);
  }

  const int prm = (lr >> 1) & 3;           // == ((row)>>1)&3 for row = 16q + lr
  for (int kt = 0; kt < nk; ++kt){
    __syncthreads();                       // staged buf[cur] visible; prev buf free
    if (kt + 1 < nk){
      int k0 = (kt + 1) * 32;
      int nb = cur ^ 1;
      #pragma unroll
      for (int c = 0; c < 2; ++c){
        int e = c*2048 + e0;
        int r = e >> 5;
        int cl = (sl ^ ((r >> 1) & 3)) << 3;
        load_lds16(Ab + (size_t)r*K + k0 + cl, lA0 + nb*4096 + e);
        load_lds16(Bb + (size_t)r*K + k0 + cl, lB0 + nb*4096 + e);
      }
    }
    bf16x8 af[4], bfr[4];
    #pragma unroll
    for (int mi = 0; mi < 4; ++mi)
      af[mi] = *(const bf16x8*)&lA0[cur*4096 + (wm*64 + mi*16 + lr)*32 + (lg ^ prm)*8];
    #pragma unroll
    for (int ni = 0; ni < 4; ++ni)
      bfr[ni] = *(const bf16x8*)&lB0[cur*4096 + (wn*64 + ni*16 + lr)*32 + (lg ^ prm)*8];
    #pragma unroll
    for (int mi = 0; mi < 4; ++mi)
      #pragma unroll
      for (int ni = 0; ni < 4; ++ni)
        acc[mi][ni] = __builtin_amdgcn_mfma_f32_16x16x32_bf16(af[mi], bfr[ni], acc[mi][ni], 0, 0, 0);
    cur ^= 1;
  }

  // ---- packed epilogue. D frag: row = lg*4 + r (+16*mi), col = lr (+16*ni) [m89] ----
  __syncthreads();                         // all waves done with staging LDS
  const int rw = blockIdx.y*128 + wm*64;
  const int cw = blockIdx.x*128 + wn*64;

  if (MODE == 0){
    unsigned short* st = smraw + wv*4608;  // 64 rows x stride 72 (144B, 16B-aligned)
    #pragma unroll
    for (int mi = 0; mi < 4; ++mi)
      #pragma unroll
      for (int ni = 0; ni < 4; ++ni)
        #pragma unroll
        for (int r = 0; r < 4; ++r)
          st[(mi*16 + lg*4 + r)*72 + ni*16 + lr] = f2bf(acc[mi][ni][r]);
    const bool hi = (cw >= DI_);
    unsigned short* base = hi ? (oB1 + (size_t)rw*DI_ + (cw - DI_))
                              : (oB0 + (size_t)rw*DI_ + cw);
    #pragma unroll
    for (int i = 0; i < 8; ++i){
      int lrow = i*8 + (lane >> 3);
      u16x8 v = *(const u16x8*)&st[lrow*72 + (lane & 7)*8];
      if (hi){
        #pragma unroll
        for (int j = 0; j < 8; ++j) v[j] = f2bf(silu_f(bf2f(v[j])));
      }
      *(u16x8*)(base + (size_t)lrow*DI_ + (lane & 7)*8) = v;
    }
  } else {
    float* st = (float*)smraw + wv*2304;   // 64 rows x stride 36 (144B, 16B-aligned)
    #pragma unroll
    for (int h = 0; h < 2; ++h){           // two 32-col half-passes (fp32 = 2x bytes)
      #pragma unroll
      for (int mi = 0; mi < 4; ++mi)
        #pragma unroll
        for (int nn = 0; nn < 2; ++nn){
          int ni = h*2 + nn;
          int col = cw + ni*16 + lr;
          #pragma unroll
          for (int r = 0; r < 4; ++r){
            float v = acc[mi][ni][r];
            if (MODE == 2) v = softplus_f(v + bias[col]);
            st[(mi*16 + lg*4 + r)*36 + nn*16 + lr] = v;
          }
        }
      // wave-private region: compiler orders ds_write/ds_read via lgkmcnt
      #pragma unroll
      for (int i = 0; i < 8; ++i){
        int lrow = i*8 + (lane >> 3);
        int col = cw + h*32 + (lane & 7)*4;
        float4 v = *(const float4*)&st[lrow*36 + (lane & 7)*4];
        if (MODE != 1 || col < nvalid)
          *(float4*)(oF + (size_t)(rw + lrow)*ldo + col) = v;
      }
    }
  }
}

// ---------------- depthwise causal conv(4) + SiLU ----------------
__global__ __launch_bounds__(256) void k_conv(const unsigned short* __restrict__ xb, const float* __restrict__ w,
                                              const float* __restrict__ cb, unsigned short* __restrict__ ub)
{
  const int d  = blockIdx.x*256 + threadIdx.x;
  const int t0 = blockIdx.y*64;
  const int b  = blockIdx.z;
  const float w0 = w[d*4+0], w1 = w[d*4+1], w2 = w[d*4+2], w3 = w[d*4+3], bias = cb[d];
  const size_t base = (size_t)(b*SEQ_)*DI_ + d;
  float xm3 = 0.f, xm2 = 0.f, xm1 = 0.f;
  if (t0 > 0){
    xm3 = bf2f(xb[base + (size_t)(t0-3)*DI_]);
    xm2 = bf2f(xb[base + (size_t)(t0-2)*DI_]);
    xm1 = bf2f(xb[base + (size_t)(t0-1)*DI_]);
  }
  for (int t = t0; t < t0 + 64; ++t){
    float xc = bf2f(xb[base + (size_t)t*DI_]);
    float acc = w0*xm3 + w1*xm2 + w2*xm1 + w3*xc + bias;
    ub[base + (size_t)t*DI_] = f2bf(silu_f(acc));
    xm3 = xm2; xm2 = xm1; xm1 = xc;
  }
}

// ---------------- chunked selective scan ----------------
__global__ __launch_bounds__(256) void k_scanA(const float* __restrict__ dtf, const unsigned short* __restrict__ ub,
                                               const float* __restrict__ xdbl, const float* __restrict__ alog,
                                               float* __restrict__ hloc, float* __restrict__ pprod)
{
  const int d = blockIdx.x*256 + threadIdx.x;
  const int c = blockIdx.y, b = blockIdx.z;
  __shared__ float sB[LCH][DSTATE];
  const size_t rowbase = (size_t)(b*SEQ_ + c*LCH);
  for (int i = threadIdx.x; i < LCH*DSTATE; i += 256){
    int t = i >> 4, n = i & 15;
    sB[t][n] = xdbl[(rowbase + t)*XDBLN + DTRANK + n];
  }
  __syncthreads();
  float a[16], h[16], p[16];
  #pragma unroll
  for (int n = 0; n < 16; ++n){
    a[n] = -__expf(alog[(size_t)d*16 + n]);
    h[n] = 0.f; p[n] = 1.f;
  }
  const size_t base = rowbase*DI_ + d;
  for (int t = 0; t < LCH; ++t){
    float dtv = dtf[base + (size_t)t*DI_];
    float uv  = bf2f(ub[base + (size_t)t*DI_]);
    float du  = dtv*uv;
    #pragma unroll
    for (int n = 0; n < 16; ++n){
      float da = __expf(dtv*a[n]);
      h[n] = da*h[n] + du*sB[t][n];
      p[n] *= da;
    }
  }
  const size_t o = ((size_t)(b*NCH + c)*DI_ + d)*16;
  #pragma unroll
  for (int n = 0; n < 16; ++n){ hloc[o+n] = h[n]; pprod[o+n] = p[n]; }
}

__global__ __launch_bounds__(256) void k_scanB(const float* __restrict__ hloc, const float* __restrict__ pprod,
                                               float* __restrict__ hinit)
{
  int i = blockIdx.x*256 + threadIdx.x;  // over BATCH_*DI_*16
  int b = i >> 15;
  int r = i & 32767;
  int d = r >> 4, n = r & 15;
  float H = 0.f;
  for (int c = 0; c < NCH; ++c){
    size_t o = ((size_t)(b*NCH + c)*DI_ + d)*16 + n;
    hinit[o] = H;
    H = pprod[o]*H + hloc[o];
  }
}

__global__ __launch_bounds__(256) void k_scanC(const float* __restrict__ dtf, const unsigned short* __restrict__ ub,
                                               const float* __restrict__ xdbl, const float* __restrict__ alog,
                                               const float* __restrict__ hinit, const float* __restrict__ Dvec,
                                               const unsigned short* __restrict__ sresb, unsigned short* __restrict__ yg)
{
  const int d = blockIdx.x*256 + threadIdx.x;
  const int c = blockIdx.y, b = blockIdx.z;
  __shared__ float sBC[LCH][32];   // [t][0..15]=B, [16..31]=C
  const size_t rowbase = (size_t)(b*SEQ_ + c*LCH);
  for (int i = threadIdx.x; i < LCH*32; i += 256){
    int t = i >> 5, j = i & 31;
    sBC[t][j] = xdbl[(rowbase + t)*XDBLN + DTRANK + j];
  }
  __syncthreads();
  float a[16], h[16];
  const size_t o = ((size_t)(b*NCH + c)*DI_ + d)*16;
  #pragma unroll
  for (int n = 0; n < 16; ++n){
    a[n] = -__expf(alog[(size_t)d*16 + n]);
    h[n] = hinit[o + n];
  }
  const float Dd = Dvec[d];
  const size_t base = rowbase*DI_ + d;
  for (int t = 0; t < LCH; ++t){
    float dtv = dtf[base + (size_t)t*DI_];
    float uv  = bf2f(ub[base + (size_t)t*DI_]);
    float du  = dtv*uv;
    float y = 0.f;
    #pragma unroll
    for (int n = 0; n < 16; ++n){
      float da = __expf(dtv*a[n]);
      h[n] = da*h[n] + du*sBC[t][n];
      y += h[n]*sBC[t][16+n];
    }
    y += Dd*uv;
    float g = bf2f(sresb[base + (size_t)t*DI_]);
    yg[base + (size_t)t*DI_] = f2bf(y*g);
  }
}

extern "C" void kernel_launch(void* const* d_in, const int* in_sizes, int n_in,
                              void* d_out, int out_size, void* d_ws, size_t ws_size,
                              hipStream_t stream)
{
  const float* hs    = (const float*)d_in[0];
  const float* Win   = (const float*)d_in[1];
  const float* convw = (const float*)d_in[2];
  const float* convb = (const float*)d_in[3];
  const float* Wx    = (const float*)d_in[4];
  const float* Wdt   = (const float*)d_in[5];
  const float* bdt   = (const float*)d_in[6];
  const float* Alog  = (const float*)d_in[7];
  const float* Dvec  = (const float*)d_in[8];
  const float* Wout  = (const float*)d_in[9];
  float* out = (float*)d_out;

  char* p = (char*)d_ws;
  auto take = [&](size_t bytes) -> char* {
    char* r = p; p += (bytes + 255) & ~(size_t)255; return r;
  };
  unsigned short* hsb   = (unsigned short*)take((size_t)MTOT*DM_*2);
  unsigned short* winb  = (unsigned short*)take((size_t)2*DI_*DM_*2);
  unsigned short* woutb = (unsigned short*)take((size_t)DM_*DI_*2);
  unsigned short* wxpb  = (unsigned short*)take((size_t)128*DI_*2);
  unsigned short* wdtb  = (unsigned short*)take((size_t)DI_*DTRANK*2);
  unsigned short* xb    = (unsigned short*)take((size_t)MTOT*DI_*2);
  unsigned short* sresb = (unsigned short*)take((size_t)MTOT*DI_*2);
  unsigned short* ub    = (unsigned short*)take((size_t)MTOT*DI_*2);
  float*          xdbl  = (float*)take((size_t)MTOT*XDBLN*4);
  unsigned short* xdtb  = (unsigned short*)take((size_t)MTOT*DTRANK*2);
  float*          dtf   = (float*)take((size_t)MTOT*DI_*4);
  float*          hloc  = (float*)take((size_t)BATCH_*NCH*DI_*16*4);
  float*          pprod = (float*)take((size_t)BATCH_*NCH*DI_*16*4);
  float*          hinit = (float*)take((size_t)BATCH_*NCH*DI_*16*4);
  unsigned short* yg    = (unsigned short*)take((size_t)MTOT*DI_*2);
  if ((size_t)(p - (char*)d_ws) > ws_size) return;

  // dtype converts
  k_f2bf <<<(MTOT*DM_/4 + 255)/256, 256, 0, stream>>>(hs,  hsb,  MTOT*DM_);
  k_f2bf <<<(2*DI_*DM_/4 + 255)/256, 256, 0, stream>>>(Win, winb, 2*DI_*DM_);
  k_f2bf <<<(DM_*DI_/4 + 255)/256, 256, 0, stream>>>(Wout, woutb, DM_*DI_);
  k_f2bf <<<(DI_*DTRANK/4 + 255)/256, 256, 0, stream>>>(Wdt, wdtb, DI_*DTRANK);
  k_wxpad<<<(128*DI_/4)/256, 256, 0, stream>>>(Wx, wxpb);

  // in-projection: xr = hs @ W_in^T ; split -> x (bf16), silu(res) (bf16)
  k_gemm<0><<<dim3(32, 32), 256, 0, stream>>>(hsb, winb, DM_, nullptr, xb, sresb, nullptr, 0, 0);

  // depthwise conv + silu -> u (bf16)
  k_conv<<<dim3(DI_/256, SEQ_/64, BATCH_), 256, 0, stream>>>(xb, convw, convb, ub);

  // x_dbl = u @ W_x^T (N padded 96->128)
  k_gemm<1><<<dim3(1, 32), 256, 0, stream>>>(ub, wxpb, DI_, xdbl, nullptr, nullptr, nullptr, XDBLN, XDBLN);
  k_xdt<<<(MTOT*DTRANK/4)/256, 256, 0, stream>>>(xdbl, xdtb);

  // dt = softplus(x_dbl[:, :64] @ W_dt^T + b_dt)
  k_gemm<2><<<dim3(16, 32), 256, 0, stream>>>(xdtb, wdtb, DTRANK, dtf, nullptr, nullptr, bdt, DI_, DI_);

  // chunked selective scan
  k_scanA<<<dim3(DI_/256, NCH, BATCH_), 256, 0, stream>>>(dtf, ub, xdbl, Alog, hloc, pprod);
  k_scanB<<<(BATCH_*DI_*16)/256, 256, 0, stream>>>(hloc, pprod, hinit);
  k_scanC<<<dim3(DI_/256, NCH, BATCH_), 256, 0, stream>>>(dtf, ub, xdbl, Alog, hinit, Dvec, sresb, yg);

  // final projection: out = (y * silu(res)) @ W_out^T
  k_gemm<3><<<dim3(DM_/128, 32), 256, 0, stream>>>(yg, woutb, DI_, out, nullptr, nullptr, nullptr, DM_, DM_);
}